// Round 5
// baseline (732.882 us; speedup 1.0000x reference)
//
#include <hip/hip_runtime.h>
#include <math.h>

#define HIDDEN 1000
#define K4 250        // HIDDEN/4 float4 per row
#define NBLK 1000     // one block per neuron; __launch_bounds__(256,4) -> 1024 resident capacity

__device__ __forceinline__ float sigmoidf_(float x) {
  return 1.f / (1.f + expf(-x));
}

// Wave-level triple-row dot: 3 weight rows vs one shared vector, interleaved
// loads (4 float4/iter, unroll x2 => ~8 in flight). Results broadcast to all lanes.
__device__ __forceinline__ void wave_dot3(const float4* __restrict__ w0,
                                          const float4* __restrict__ w1,
                                          const float4* __restrict__ w2,
                                          const float4* __restrict__ v,
                                          int lane,
                                          float& r0, float& r1, float& r2) {
  float a0 = 0.f, a1 = 0.f, a2 = 0.f;
  #pragma unroll 2
  for (int c = lane; c < K4; c += 64) {
    float4 hv = v[c];
    float4 x0 = w0[c];
    float4 x1 = w1[c];
    float4 x2 = w2[c];
    a0 = fmaf(x0.x, hv.x, fmaf(x0.y, hv.y, fmaf(x0.z, hv.z, fmaf(x0.w, hv.w, a0))));
    a1 = fmaf(x1.x, hv.x, fmaf(x1.y, hv.y, fmaf(x1.z, hv.z, fmaf(x1.w, hv.w, a1))));
    a2 = fmaf(x2.x, hv.x, fmaf(x2.y, hv.y, fmaf(x2.z, hv.z, fmaf(x2.w, hv.w, a2))));
  }
  #pragma unroll
  for (int o = 32; o; o >>= 1) {
    a0 += __shfl_xor(a0, o);
    a1 += __shfl_xor(a1, o);
    a2 += __shfl_xor(a2, o);
  }
  r0 = a0; r1 = a1; r2 = a2;
}

// Persistent kernel: block j owns neuron j across all layers.
//   Stage A: gh_l = Whh[l] rows (j,1000+j,2000+j) . hiddens[l] for l=0..7
//            (wave0: l0 [+gate h0 -> barrier cnt0] and l7; waves1-3: l1..l6).
//   Stage l=1..7: W_ih[l] rows prefetched in regs one stage early; spin on
//            cnt[l-1]==NBLK; load h_{l-1} (agent-coherent); FMA+reduce+gate;
//            publish h_l (agent store) + release count. Layer 7 adds flow.
__global__ __launch_bounds__(256, 4)
void gru_persist(const float* __restrict__ x,        // [2]
                 const float* __restrict__ hiddens,  // [8*1000]
                 const float* __restrict__ Wih0,     // [3000*2]
                 const float* __restrict__ Wih,      // [7*3000*1000]
                 const float* __restrict__ Whh,      // [8*3000*1000]
                 const float* __restrict__ bih,      // [8*3000]
                 const float* __restrict__ bhh,      // [8*3000]
                 const float* __restrict__ Wout,     // [1000]
                 const float* __restrict__ bout,     // [1]
                 float* __restrict__ h_buf,          // ws [8*1000]
                 unsigned* __restrict__ cnt,         // ws [8], zeroed per call
                 float* __restrict__ out)            // [8001]
{
  const int t    = threadIdx.x;
  const int wv   = t >> 6;
  const int lane = t & 63;
  const int j    = blockIdx.x;

  __shared__ float s_gh[8][3];   // gh (incl. bhh) per layer, for this neuron
  __shared__ float s_red[4][3];

  const float4* WI4 = reinterpret_cast<const float4*>(Wih);
  const float4* WH4 = reinterpret_cast<const float4*>(Whh);
  const float4* HV4 = reinterpret_cast<const float4*>(hiddens);

  // init flow accumulator (visible before any stage-7 atomicAdd via the
  // release/acquire chain of barriers 0..6 that block 0 participates in)
  if (j == 0 && t == 128) {
    __hip_atomic_store(&out[0], bout[0], __ATOMIC_RELAXED, __HIP_MEMORY_SCOPE_AGENT);
  }

  // prefetch W_ih[layer1] rows for stage 1
  float4 pr = {0,0,0,0}, pz = {0,0,0,0}, pn = {0,0,0,0};
  if (t < K4) {
    pr = WI4[((size_t)(0 * 3000) +    0 + j) * K4 + t];
    pz = WI4[((size_t)(0 * 3000) + 1000 + j) * K4 + t];
    pn = WI4[((size_t)(0 * 3000) + 2000 + j) * K4 + t];
  }

  // ---------------- stage A: all gh dots ----------------
  if (wv == 0) {
    // layer 0 rows + gate -> h0, publish + count
    float d0, d1, d2;
    wave_dot3(&WH4[((size_t)0 +    0 + j) * K4],
              &WH4[((size_t)0 + 1000 + j) * K4],
              &WH4[((size_t)0 + 2000 + j) * K4],
              &HV4[0], lane, d0, d1, d2);
    if (lane == 0) {
      const float x0 = x[0], x1 = x[1];
      float gir = fmaf(Wih0[2*j],          x0, Wih0[2*j+1]          * x1) + bih[j];
      float giz = fmaf(Wih0[2*(1000+j)],   x0, Wih0[2*(1000+j)+1]   * x1) + bih[1000 + j];
      float gin = fmaf(Wih0[2*(2000+j)],   x0, Wih0[2*(2000+j)+1]   * x1) + bih[2000 + j];
      float r = sigmoidf_(gir + d0 + bhh[j]);
      float z = sigmoidf_(giz + d1 + bhh[1000 + j]);
      float n = tanhf(gin + r * (d2 + bhh[2000 + j]));
      float h = (1.f - z) * n + z * hiddens[j];
      __hip_atomic_store(&h_buf[j], h, __ATOMIC_RELAXED, __HIP_MEMORY_SCOPE_AGENT);
      out[1 + j] = h;
      __hip_atomic_fetch_add(&cnt[0], 1u, __ATOMIC_RELEASE, __HIP_MEMORY_SCOPE_AGENT);
    }
    // layer 7 rows
    float e0, e1, e2;
    wave_dot3(&WH4[((size_t)(7*3000) +    0 + j) * K4],
              &WH4[((size_t)(7*3000) + 1000 + j) * K4],
              &WH4[((size_t)(7*3000) + 2000 + j) * K4],
              &HV4[7 * K4], lane, e0, e1, e2);
    if (lane == 0) {
      s_gh[7][0] = e0 + bhh[7*3000 +    0 + j];
      s_gh[7][1] = e1 + bhh[7*3000 + 1000 + j];
      s_gh[7][2] = e2 + bhh[7*3000 + 2000 + j];
    }
  } else {
    const int l0 = 2 * wv - 1;          // wv1: l1,l2  wv2: l3,l4  wv3: l5,l6
    #pragma unroll
    for (int li = 0; li < 2; ++li) {
      const int l = l0 + li;
      float d0, d1, d2;
      wave_dot3(&WH4[((size_t)(l*3000) +    0 + j) * K4],
                &WH4[((size_t)(l*3000) + 1000 + j) * K4],
                &WH4[((size_t)(l*3000) + 2000 + j) * K4],
                &HV4[l * K4], lane, d0, d1, d2);
      if (lane == 0) {
        s_gh[l][0] = d0 + bhh[l*3000 +    0 + j];
        s_gh[l][1] = d1 + bhh[l*3000 + 1000 + j];
        s_gh[l][2] = d2 + bhh[l*3000 + 2000 + j];
      }
    }
  }

  // ---------------- stages 1..7 ----------------
  #pragma unroll
  for (int l = 1; l <= 7; ++l) {
    float bi0 = 0.f, bi1 = 0.f, bi2 = 0.f, hprev = 0.f;
    if (t == 0) {
      bi0   = bih[l*3000 +    0 + j];
      bi1   = bih[l*3000 + 1000 + j];
      bi2   = bih[l*3000 + 2000 + j];
      hprev = hiddens[(size_t)l * HIDDEN + j];
      long spin = 0;
      while (__hip_atomic_load(&cnt[l-1], __ATOMIC_ACQUIRE, __HIP_MEMORY_SCOPE_AGENT) < NBLK) {
        __builtin_amdgcn_s_sleep(4);
        if (++spin > (1L << 26)) break;   // ~seconds; never expected
      }
    }
    __syncthreads();   // releases all threads; also fences stage-A s_gh writes

    // agent-coherent load of h_{l-1} (bypasses possibly-stale local caches)
    float h0 = 0.f, h1 = 0.f, h2 = 0.f, h3 = 0.f;
    const float* hs = h_buf + (size_t)(l - 1) * HIDDEN + 4 * t;
    if (t < K4) {
      h0 = __hip_atomic_load(hs + 0, __ATOMIC_RELAXED, __HIP_MEMORY_SCOPE_AGENT);
      h1 = __hip_atomic_load(hs + 1, __ATOMIC_RELAXED, __HIP_MEMORY_SCOPE_AGENT);
      h2 = __hip_atomic_load(hs + 2, __ATOMIC_RELAXED, __HIP_MEMORY_SCOPE_AGENT);
      h3 = __hip_atomic_load(hs + 3, __ATOMIC_RELAXED, __HIP_MEMORY_SCOPE_AGENT);
    }

    // prefetch W_ih[l+1] (hidden under this stage's tail + next barrier wait)
    float4 nr = {0,0,0,0}, nz = {0,0,0,0}, nn = {0,0,0,0};
    if (l < 7 && t < K4) {
      nr = WI4[((size_t)(l * 3000) +    0 + j) * K4 + t];
      nz = WI4[((size_t)(l * 3000) + 1000 + j) * K4 + t];
      nn = WI4[((size_t)(l * 3000) + 2000 + j) * K4 + t];
    }

    float a0 = 0.f, a1 = 0.f, a2 = 0.f;
    if (t < K4) {
      a0 = fmaf(pr.x, h0, fmaf(pr.y, h1, fmaf(pr.z, h2, pr.w * h3)));
      a1 = fmaf(pz.x, h0, fmaf(pz.y, h1, fmaf(pz.z, h2, pz.w * h3)));
      a2 = fmaf(pn.x, h0, fmaf(pn.y, h1, fmaf(pn.z, h2, pn.w * h3)));
    }
    #pragma unroll
    for (int o = 32; o; o >>= 1) {
      a0 += __shfl_xor(a0, o);
      a1 += __shfl_xor(a1, o);
      a2 += __shfl_xor(a2, o);
    }
    if (lane == 0) { s_red[wv][0] = a0; s_red[wv][1] = a1; s_red[wv][2] = a2; }
    __syncthreads();

    if (t == 0) {
      float gi0 = s_red[0][0] + s_red[1][0] + s_red[2][0] + s_red[3][0] + bi0;
      float gi1 = s_red[0][1] + s_red[1][1] + s_red[2][1] + s_red[3][1] + bi1;
      float gi2 = s_red[0][2] + s_red[1][2] + s_red[2][2] + s_red[3][2] + bi2;
      float r = sigmoidf_(gi0 + s_gh[l][0]);
      float z = sigmoidf_(gi1 + s_gh[l][1]);
      float n = tanhf(gi2 + r * s_gh[l][2]);
      float h = (1.f - z) * n + z * hprev;
      __hip_atomic_store(&h_buf[(size_t)l * HIDDEN + j], h,
                         __ATOMIC_RELAXED, __HIP_MEMORY_SCOPE_AGENT);
      out[1 + l * HIDDEN + j] = h;
      if (l == 7) {
        atomicAdd(&out[0], Wout[j] * h);
      } else {
        __hip_atomic_fetch_add(&cnt[l], 1u, __ATOMIC_RELEASE, __HIP_MEMORY_SCOPE_AGENT);
      }
    }
    pr = nr; pz = nz; pn = nn;
    __syncthreads();   // protect s_red reuse
  }
}

extern "C" void kernel_launch(void* const* d_in, const int* in_sizes, int n_in,
                              void* d_out, int out_size, void* d_ws, size_t ws_size,
                              hipStream_t stream) {
  const float* x       = (const float*)d_in[0];
  const float* hiddens = (const float*)d_in[1];
  const float* Wih0    = (const float*)d_in[2];
  const float* Wih     = (const float*)d_in[3];
  const float* Whh     = (const float*)d_in[4];
  const float* bih     = (const float*)d_in[5];
  const float* bhh     = (const float*)d_in[6];
  const float* Wout    = (const float*)d_in[7];
  const float* bout    = (const float*)d_in[8];
  float* out   = (float*)d_out;
  float* h_buf = (float*)d_ws;                  // 8000 floats
  unsigned* cnt = (unsigned*)(h_buf + 8000);    // 8 uints

  hipMemsetAsync(cnt, 0, 8 * sizeof(unsigned), stream);
  gru_persist<<<NBLK, 256, 0, stream>>>(x, hiddens, Wih0, Wih, Whh, bih, bhh,
                                        Wout, bout, h_buf, cnt, out);
}

// Round 6
// 431.125 us; speedup vs baseline: 1.6999x; 1.6999x over previous
//
#include <hip/hip_runtime.h>
#include <math.h>

#define HIDDEN 1000
#define K4 250        // HIDDEN/4 float4 per row
#define NBLK 1000     // one block per neuron
#define NCNT 64       // spread counters per barrier
#define CSTR 32       // counter stride in uints (128 B -> one L2 line each)
#define NBAR 7        // barriers (after layers 0..6)

__device__ __forceinline__ float sigmoidf_(float x) {
  return 1.f / (1.f + expf(-x));
}

// Wave-level triple-row dot: 3 weight rows vs one shared vector, interleaved
// loads. Results broadcast to all lanes.
__device__ __forceinline__ void wave_dot3(const float4* __restrict__ w0,
                                          const float4* __restrict__ w1,
                                          const float4* __restrict__ w2,
                                          const float4* __restrict__ v,
                                          int lane,
                                          float& r0, float& r1, float& r2) {
  float a0 = 0.f, a1 = 0.f, a2 = 0.f;
  #pragma unroll 2
  for (int c = lane; c < K4; c += 64) {
    float4 hv = v[c];
    float4 x0 = w0[c];
    float4 x1 = w1[c];
    float4 x2 = w2[c];
    a0 = fmaf(x0.x, hv.x, fmaf(x0.y, hv.y, fmaf(x0.z, hv.z, fmaf(x0.w, hv.w, a0))));
    a1 = fmaf(x1.x, hv.x, fmaf(x1.y, hv.y, fmaf(x1.z, hv.z, fmaf(x1.w, hv.w, a1))));
    a2 = fmaf(x2.x, hv.x, fmaf(x2.y, hv.y, fmaf(x2.z, hv.z, fmaf(x2.w, hv.w, a2))));
  }
  #pragma unroll
  for (int o = 32; o; o >>= 1) {
    a0 += __shfl_xor(a0, o);
    a1 += __shfl_xor(a1, o);
    a2 += __shfl_xor(a2, o);
  }
  r0 = a0; r1 = a1; r2 = a2;
}

// Persistent kernel, block j owns neuron j. Barriers use 64 line-padded
// counters (block j adds to counter j&63); wave 0 polls all 64 lane-parallel.
__global__ __launch_bounds__(256, 4)
void gru_persist(const float* __restrict__ x,        // [2]
                 const float* __restrict__ hiddens,  // [8*1000]
                 const float* __restrict__ Wih0,     // [3000*2]
                 const float* __restrict__ Wih,      // [7*3000*1000]
                 const float* __restrict__ Whh,      // [8*3000*1000]
                 const float* __restrict__ bih,      // [8*3000]
                 const float* __restrict__ bhh,      // [8*3000]
                 const float* __restrict__ Wout,     // [1000]
                 const float* __restrict__ bout,     // [1]
                 float* __restrict__ h_buf,          // ws [8*1000]
                 unsigned* __restrict__ cnt,         // ws [7*64*32], zeroed/call
                 float* __restrict__ out)            // [8001]
{
  const int t    = threadIdx.x;
  const int wv   = t >> 6;
  const int lane = t & 63;
  const int j    = blockIdx.x;

  __shared__ float s_gh[8][3];
  __shared__ float s_red[4][3];

  const float4* WI4 = reinterpret_cast<const float4*>(Wih);
  const float4* WH4 = reinterpret_cast<const float4*>(Whh);
  const float4* HV4 = reinterpret_cast<const float4*>(hiddens);

  // prefetch W_ih[layer1] rows for stage 1
  float4 pr = {0,0,0,0}, pz = {0,0,0,0}, pn = {0,0,0,0};
  if (t < K4) {
    pr = WI4[((size_t)(   0 + j)) * K4 + t];
    pz = WI4[((size_t)(1000 + j)) * K4 + t];
    pn = WI4[((size_t)(2000 + j)) * K4 + t];
  }

  // ---------------- stage A: all gh dots ----------------
  if (wv == 0) {
    float d0, d1, d2;
    wave_dot3(&WH4[((size_t)(   0 + j)) * K4],
              &WH4[((size_t)(1000 + j)) * K4],
              &WH4[((size_t)(2000 + j)) * K4],
              &HV4[0], lane, d0, d1, d2);
    if (lane == 0) {
      const float x0 = x[0], x1 = x[1];
      float gir = fmaf(Wih0[2*j],        x0, Wih0[2*j+1]        * x1) + bih[j];
      float giz = fmaf(Wih0[2*(1000+j)], x0, Wih0[2*(1000+j)+1] * x1) + bih[1000 + j];
      float gin = fmaf(Wih0[2*(2000+j)], x0, Wih0[2*(2000+j)+1] * x1) + bih[2000 + j];
      float r = sigmoidf_(gir + d0 + bhh[j]);
      float z = sigmoidf_(giz + d1 + bhh[1000 + j]);
      float n = tanhf(gin + r * (d2 + bhh[2000 + j]));
      float h = (1.f - z) * n + z * hiddens[j];
      if (j == 0) {
        __hip_atomic_store(&out[0], bout[0], __ATOMIC_RELAXED, __HIP_MEMORY_SCOPE_AGENT);
      }
      __hip_atomic_store(&h_buf[j], h, __ATOMIC_RELAXED, __HIP_MEMORY_SCOPE_AGENT);
      out[1 + j] = h;
      __hip_atomic_fetch_add(&cnt[(size_t)(j & 63) * CSTR], 1u,
                             __ATOMIC_RELEASE, __HIP_MEMORY_SCOPE_AGENT);
    }
    // layer-7 gh rows
    float e0, e1, e2;
    wave_dot3(&WH4[((size_t)(7*3000 +    0 + j)) * K4],
              &WH4[((size_t)(7*3000 + 1000 + j)) * K4],
              &WH4[((size_t)(7*3000 + 2000 + j)) * K4],
              &HV4[7 * K4], lane, e0, e1, e2);
    if (lane == 0) {
      s_gh[7][0] = e0 + bhh[7*3000 +    0 + j];
      s_gh[7][1] = e1 + bhh[7*3000 + 1000 + j];
      s_gh[7][2] = e2 + bhh[7*3000 + 2000 + j];
    }
  } else {
    const int l0 = 2 * wv - 1;          // wv1: l1,l2  wv2: l3,l4  wv3: l5,l6
    #pragma unroll
    for (int li = 0; li < 2; ++li) {
      const int l = l0 + li;
      float d0, d1, d2;
      wave_dot3(&WH4[((size_t)(l*3000 +    0 + j)) * K4],
                &WH4[((size_t)(l*3000 + 1000 + j)) * K4],
                &WH4[((size_t)(l*3000 + 2000 + j)) * K4],
                &HV4[l * K4], lane, d0, d1, d2);
      if (lane == 0) {
        s_gh[l][0] = d0 + bhh[l*3000 +    0 + j];
        s_gh[l][1] = d1 + bhh[l*3000 + 1000 + j];
        s_gh[l][2] = d2 + bhh[l*3000 + 2000 + j];
      }
    }
  }

  // ---------------- stages 1..7 ----------------
  #pragma unroll
  for (int l = 1; l <= 7; ++l) {
    float bi0 = 0.f, bi1 = 0.f, bi2 = 0.f, hprev = 0.f;
    if (t == 0) {
      bi0   = bih[l*3000 +    0 + j];
      bi1   = bih[l*3000 + 1000 + j];
      bi2   = bih[l*3000 + 2000 + j];
      hprev = hiddens[(size_t)l * HIDDEN + j];
    }
    if (wv == 0) {
      // lane i polls counter i of barrier l-1 (each on its own 128B line)
      const unsigned tgt = (lane < 40) ? 16u : 15u;
      const unsigned* c = cnt + (size_t)(l - 1) * NCNT * CSTR + (size_t)lane * CSTR;
      int spin = 0;
      for (;;) {
        unsigned v = __hip_atomic_load(c, __ATOMIC_RELAXED, __HIP_MEMORY_SCOPE_AGENT);
        if (__all(v >= tgt)) break;
        __builtin_amdgcn_s_sleep(8);
        if (++spin > (1 << 22)) break;   // safety bailout, never expected
      }
    }
    __syncthreads();
    __builtin_amdgcn_fence(__ATOMIC_ACQUIRE, "agent");

    // plain vector load of h_{l-1} (ordered after the acquire fence)
    float4 hv = {0,0,0,0};
    if (t < K4) {
      hv = *reinterpret_cast<const float4*>(h_buf + (size_t)(l - 1) * HIDDEN + 4 * t);
    }

    // prefetch W_ih[l+1] rows (hidden under this stage's tail + next wait)
    float4 nr = {0,0,0,0}, nz = {0,0,0,0}, nn = {0,0,0,0};
    if (l < 7 && t < K4) {
      nr = WI4[((size_t)(l * 3000 +    0 + j)) * K4 + t];
      nz = WI4[((size_t)(l * 3000 + 1000 + j)) * K4 + t];
      nn = WI4[((size_t)(l * 3000 + 2000 + j)) * K4 + t];
    }

    float a0 = 0.f, a1 = 0.f, a2 = 0.f;
    if (t < K4) {
      a0 = fmaf(pr.x, hv.x, fmaf(pr.y, hv.y, fmaf(pr.z, hv.z, pr.w * hv.w)));
      a1 = fmaf(pz.x, hv.x, fmaf(pz.y, hv.y, fmaf(pz.z, hv.z, pz.w * hv.w)));
      a2 = fmaf(pn.x, hv.x, fmaf(pn.y, hv.y, fmaf(pn.z, hv.z, pn.w * hv.w)));
    }
    #pragma unroll
    for (int o = 32; o; o >>= 1) {
      a0 += __shfl_xor(a0, o);
      a1 += __shfl_xor(a1, o);
      a2 += __shfl_xor(a2, o);
    }
    if (lane == 0) { s_red[wv][0] = a0; s_red[wv][1] = a1; s_red[wv][2] = a2; }
    __syncthreads();

    if (t == 0) {
      float gi0 = s_red[0][0] + s_red[1][0] + s_red[2][0] + s_red[3][0] + bi0;
      float gi1 = s_red[0][1] + s_red[1][1] + s_red[2][1] + s_red[3][1] + bi1;
      float gi2 = s_red[0][2] + s_red[1][2] + s_red[2][2] + s_red[3][2] + bi2;
      float r = sigmoidf_(gi0 + s_gh[l][0]);
      float z = sigmoidf_(gi1 + s_gh[l][1]);
      float n = tanhf(gi2 + r * s_gh[l][2]);
      float h = (1.f - z) * n + z * hprev;
      __hip_atomic_store(&h_buf[(size_t)l * HIDDEN + j], h,
                         __ATOMIC_RELAXED, __HIP_MEMORY_SCOPE_AGENT);
      out[1 + l * HIDDEN + j] = h;
      if (l == 7) {
        atomicAdd(&out[0], Wout[j] * h);
      } else {
        __hip_atomic_fetch_add(&cnt[(size_t)l * NCNT * CSTR + (size_t)(j & 63) * CSTR],
                               1u, __ATOMIC_RELEASE, __HIP_MEMORY_SCOPE_AGENT);
      }
    }
    pr = nr; pz = nz; pn = nn;
    __syncthreads();   // protect s_red reuse
  }
}

extern "C" void kernel_launch(void* const* d_in, const int* in_sizes, int n_in,
                              void* d_out, int out_size, void* d_ws, size_t ws_size,
                              hipStream_t stream) {
  const float* x       = (const float*)d_in[0];
  const float* hiddens = (const float*)d_in[1];
  const float* Wih0    = (const float*)d_in[2];
  const float* Wih     = (const float*)d_in[3];
  const float* Whh     = (const float*)d_in[4];
  const float* bih     = (const float*)d_in[5];
  const float* bhh     = (const float*)d_in[6];
  const float* Wout    = (const float*)d_in[7];
  const float* bout    = (const float*)d_in[8];
  float* out    = (float*)d_out;
  float* h_buf  = (float*)d_ws;                 // 8000 floats
  unsigned* cnt = (unsigned*)(h_buf + 8000);    // 7*64*32 uints = 56 KB

  hipMemsetAsync(cnt, 0, (size_t)NBAR * NCNT * CSTR * sizeof(unsigned), stream);
  gru_persist<<<NBLK, 256, 0, stream>>>(x, hiddens, Wih0, Wih, Whh, bih, bhh,
                                        Wout, bout, h_buf, cnt, out);
}

// Round 7
// 78.811 us; speedup vs baseline: 9.2992x; 5.4703x over previous
//
#include <hip/hip_runtime.h>
#include <math.h>

#define HIDDEN 1000
#define K4 250        // HIDDEN / 4 float4s per row
#define WARMB 2048    // L3-warm blocks for Wih inside phase A

__device__ __forceinline__ float sigmoidf_(float x) {
  return 1.f / (1.f + expf(-x));
}

// Wave-level dot product of two 1000-float vectors (both 16B aligned).
// Deep sequential load stream; returns full sum in ALL lanes.
__device__ __forceinline__ float wave_dot1000(const float* __restrict__ w,
                                              const float* __restrict__ v,
                                              int lane) {
  const float4* w4 = reinterpret_cast<const float4*>(w);
  const float4* v4 = reinterpret_cast<const float4*>(v);
  float acc = 0.f;
  for (int c = lane; c < K4; c += 64) {
    float4 a = w4[c];
    float4 b = v4[c];
    acc = fmaf(a.x, b.x, acc);
    acc = fmaf(a.y, b.y, acc);
    acc = fmaf(a.z, b.z, acc);
    acc = fmaf(a.w, b.w, acc);
  }
  #pragma unroll
  for (int off = 32; off; off >>= 1) acc += __shfl_xor(acc, off);
  return acc;
}

// Phase A (BW phase, wave-per-row deep streams):
//   blocks [0,250):        layer-0 neurons (3 gh dots + tiny gi + gate -> h0)
//   blocks [250,5500):     gh rows for layers 1..7 -> gh_ws (bhh folded in)
//   blocks [5500,5500+WARMB): stream W_ih into L3 (keep-alive, no stores)
__global__ void gru_phaseA(const float* __restrict__ x,        // [2]
                           const float* __restrict__ hiddens,  // [8*1000]
                           const float* __restrict__ Wih0,     // [3000*2]
                           const float* __restrict__ Wih,      // [7*3000*1000]
                           const float* __restrict__ Whh,      // [8*3000*1000]
                           const float* __restrict__ bih,      // [8*3000]
                           const float* __restrict__ bhh,      // [8*3000]
                           const float* __restrict__ bout,     // [1]
                           float* __restrict__ gh_ws,          // [7*3000]
                           float* __restrict__ h_buf,          // [8*1000]
                           float* __restrict__ out)            // [8001]
{
  const int wave = threadIdx.x >> 6;
  const int lane = threadIdx.x & 63;
  const int b = blockIdx.x;

  if (b < 250) {
    const int j = b * 4 + wave;            // neuron 0..999
    const float* h0 = hiddens;             // layer 0 prev hidden
    float ghr = wave_dot1000(Whh + (size_t)(j)        * HIDDEN, h0, lane) + bhh[j];
    float ghz = wave_dot1000(Whh + (size_t)(1000 + j) * HIDDEN, h0, lane) + bhh[1000 + j];
    float ghn = wave_dot1000(Whh + (size_t)(2000 + j) * HIDDEN, h0, lane) + bhh[2000 + j];
    if (lane == 0) {
      const float x0 = x[0], x1 = x[1];
      float gir = Wih0[2*j]        * x0 + Wih0[2*j+1]        * x1 + bih[j];
      float giz = Wih0[2*(1000+j)] * x0 + Wih0[2*(1000+j)+1] * x1 + bih[1000 + j];
      float gin = Wih0[2*(2000+j)] * x0 + Wih0[2*(2000+j)+1] * x1 + bih[2000 + j];
      float r = sigmoidf_(gir + ghr);
      float z = sigmoidf_(giz + ghz);
      float n = tanhf(gin + r * ghn);
      float h = (1.f - z) * n + z * h0[j];
      h_buf[j] = h;
      out[1 + j] = h;
      if (j == 0) out[0] = bout[0];        // init flow accumulator
    }
  } else if (b < 5500) {
    const int rg = (b - 250) * 4 + wave;   // 0..20999
    const int l = rg / 3000 + 1;           // layer 1..7
    const int r = rg % 3000;               // row within layer
    const float* hl = hiddens + (size_t)l * HIDDEN;
    float gh = wave_dot1000(Whh + ((size_t)l * 3000 + r) * HIDDEN, hl, lane)
             + bhh[l * 3000 + r];
    if (lane == 0) gh_ws[rg] = gh;
  } else {
    // L3-warm W_ih: coalesced grid-stride float4 stream, kept alive, no store.
    const float4* WI4 = reinterpret_cast<const float4*>(Wih);
    const size_t NW4 = (size_t)7 * 3000 * K4;          // 5,250,000 float4s
    size_t idx = (size_t)(b - 5500) * 256 + threadIdx.x;
    float acc = 0.f;
    for (; idx < NW4; idx += (size_t)WARMB * 256) {
      float4 w = WI4[idx];
      acc += w.x + w.y + w.z + w.w;
    }
    asm volatile("" :: "v"(acc));   // keep the loads live (no DCE)
  }
}

// One layer (l in 1..7), latency phase: block per neuron, one-shot wide load
// (each thread 4 independent float4s) + shuffle/LDS reduce + gate.
// Layer 7 also accumulates flow into out[0] (pre-set to b_out in phase A).
__global__ __launch_bounds__(256)
void gru_layer2(const int l,
                const float* __restrict__ hiddens,  // [8*1000]
                const float* __restrict__ Wih,      // [7*3000*1000]
                const float* __restrict__ bih,      // [8*3000]
                const float* __restrict__ gh_ws,    // [7*3000] (bhh included)
                const float* __restrict__ Wout,     // [1000]
                float* __restrict__ h_buf,          // [8*1000]
                float* __restrict__ out)            // [8001]
{
  const int t = threadIdx.x;
  const int j = blockIdx.x;                // neuron 0..999
  const float4* W4  = reinterpret_cast<const float4*>(
      Wih + (size_t)(l - 1) * 3000 * HIDDEN);
  const float4* hin = reinterpret_cast<const float4*>(
      h_buf + (size_t)(l - 1) * HIDDEN);

  float aR = 0.f, aZ = 0.f, aN = 0.f;
  if (t < K4) {
    float4 hv = hin[t];
    float4 wr = W4[(size_t)(j)        * K4 + t];
    float4 wz = W4[(size_t)(1000 + j) * K4 + t];
    float4 wn = W4[(size_t)(2000 + j) * K4 + t];
    aR = fmaf(wr.x, hv.x, fmaf(wr.y, hv.y, fmaf(wr.z, hv.z, wr.w * hv.w)));
    aZ = fmaf(wz.x, hv.x, fmaf(wz.y, hv.y, fmaf(wz.z, hv.z, wz.w * hv.w)));
    aN = fmaf(wn.x, hv.x, fmaf(wn.y, hv.y, fmaf(wn.z, hv.z, wn.w * hv.w)));
  }
  #pragma unroll
  for (int off = 32; off; off >>= 1) {
    aR += __shfl_xor(aR, off);
    aZ += __shfl_xor(aZ, off);
    aN += __shfl_xor(aN, off);
  }
  __shared__ float s[4][3];
  const int wave = t >> 6, lane = t & 63;
  if (lane == 0) { s[wave][0] = aR; s[wave][1] = aZ; s[wave][2] = aN; }
  __syncthreads();
  if (t == 0) {
    float gir = s[0][0] + s[1][0] + s[2][0] + s[3][0] + bih[l*3000 + j];
    float giz = s[0][1] + s[1][1] + s[2][1] + s[3][1] + bih[l*3000 + 1000 + j];
    float gin = s[0][2] + s[1][2] + s[2][2] + s[3][2] + bih[l*3000 + 2000 + j];
    float ghr = gh_ws[(l-1)*3000 + j];
    float ghz = gh_ws[(l-1)*3000 + 1000 + j];
    float ghn = gh_ws[(l-1)*3000 + 2000 + j];
    float r = sigmoidf_(gir + ghr);
    float z = sigmoidf_(giz + ghz);
    float n = tanhf(gin + r * ghn);
    float h = (1.f - z) * n + z * hiddens[(size_t)l * HIDDEN + j];
    h_buf[l * HIDDEN + j] = h;
    out[1 + l * HIDDEN + j] = h;
    if (l == 7) atomicAdd(&out[0], Wout[j] * h);
  }
}

extern "C" void kernel_launch(void* const* d_in, const int* in_sizes, int n_in,
                              void* d_out, int out_size, void* d_ws, size_t ws_size,
                              hipStream_t stream) {
  const float* x       = (const float*)d_in[0];
  const float* hiddens = (const float*)d_in[1];
  const float* Wih0    = (const float*)d_in[2];
  const float* Wih     = (const float*)d_in[3];
  const float* Whh     = (const float*)d_in[4];
  const float* bih     = (const float*)d_in[5];
  const float* bhh     = (const float*)d_in[6];
  const float* Wout    = (const float*)d_in[7];
  const float* bout    = (const float*)d_in[8];
  float* out   = (float*)d_out;
  float* gh_ws = (float*)d_ws;          // 21000 floats (layers 1..7 gh)
  float* h_buf = gh_ws + 21000;         // 8000 floats

  gru_phaseA<<<5500 + WARMB, 256, 0, stream>>>(x, hiddens, Wih0, Wih, Whh,
                                               bih, bhh, bout, gh_ws, h_buf, out);
  for (int l = 1; l < 8; ++l) {
    gru_layer2<<<1000, 256, 0, stream>>>(l, hiddens, Wih, bih, gh_ws, Wout,
                                         h_buf, out);
  }
}

// Round 8
// 68.930 us; speedup vs baseline: 10.6323x; 1.1434x over previous
//
#include <hip/hip_runtime.h>
#include <math.h>

#define HIDDEN 1000
#define K4 250        // float4 segments per 1000-float row

__device__ __forceinline__ float sigmoidf_(float x) {
  return 1.f / (1.f + expf(-x));
}

__device__ __forceinline__ float dot4(float4 a, float4 b, float acc) {
  return fmaf(a.x, b.x, fmaf(a.y, b.y, fmaf(a.z, b.z, fmaf(a.w, b.w, acc))));
}

// Phase A: all 24000 gh rows (layers 0..7), one wave per 3 rows, fully
// unrolled segment loads (12 weight + 4 vector loads in flight, no waitcnt
// between them). Layer-0 waves own the (j,1000+j,2000+j) triple and gate h0.
__global__ __launch_bounds__(256)
void gruA_gh(const float* __restrict__ x,        // [2]
             const float* __restrict__ hiddens,  // [8*1000]
             const float* __restrict__ Wih0,     // [3000*2]
             const float* __restrict__ Whh,      // [8*3000*1000]
             const float* __restrict__ bih,      // [8*3000]
             const float* __restrict__ bhh,      // [8*3000]
             const float* __restrict__ bout,     // [1]
             float* __restrict__ gh_ws,          // [21000] layers 1..7
             float* __restrict__ h_buf,          // [8*1000]
             float* __restrict__ out)            // [8001]
{
  const int wv   = threadIdx.x >> 6;
  const int lane = threadIdx.x & 63;
  const int w    = blockIdx.x * 4 + wv;        // wave id 0..7999
  const bool tl  = (lane >= 58);               // lane+192 >= 250: seg3 invalid
  const float4 z4 = {0.f, 0.f, 0.f, 0.f};
  const float4* WH4 = reinterpret_cast<const float4*>(Whh);

  // row triple for this wave
  size_t r0i, r1i, r2i;
  int l;
  if (w < 1000) {            // layer 0: neuron triple (gate-able in-wave)
    l = 0;
    r0i = (size_t)w;
    r1i = (size_t)(1000 + w);
    r2i = (size_t)(2000 + w);
  } else {                   // layers 1..7: 3 contiguous rows
    const size_t rbase = 3000 + (size_t)(w - 1000) * 3;
    l = (int)(rbase / 3000);
    r0i = rbase; r1i = rbase + 1; r2i = rbase + 2;
  }

  // shared vector segments (layer-l previous hidden)
  const float4* v4 = reinterpret_cast<const float4*>(hiddens + (size_t)l * HIDDEN);
  float4 v0 = v4[lane];
  float4 v1 = v4[lane + 64];
  float4 v2 = v4[lane + 128];
  float4 v3 = tl ? z4 : v4[lane + 192];

  // 12 independent weight loads
  const float4* r0 = WH4 + r0i * K4;
  const float4* r1 = WH4 + r1i * K4;
  const float4* r2 = WH4 + r2i * K4;
  float4 a0 = r0[lane], a1 = r0[lane + 64], a2 = r0[lane + 128], a3 = tl ? z4 : r0[lane + 192];
  float4 b0 = r1[lane], b1 = r1[lane + 64], b2 = r1[lane + 128], b3 = tl ? z4 : r1[lane + 192];
  float4 c0 = r2[lane], c1 = r2[lane + 64], c2 = r2[lane + 128], c3 = tl ? z4 : r2[lane + 192];

  float dA = dot4(a3, v3, dot4(a2, v2, dot4(a1, v1, dot4(a0, v0, 0.f))));
  float dB = dot4(b3, v3, dot4(b2, v2, dot4(b1, v1, dot4(b0, v0, 0.f))));
  float dC = dot4(c3, v3, dot4(c2, v2, dot4(c1, v1, dot4(c0, v0, 0.f))));

  #pragma unroll
  for (int o = 32; o; o >>= 1) {
    dA += __shfl_xor(dA, o);
    dB += __shfl_xor(dB, o);
    dC += __shfl_xor(dC, o);
  }

  if (lane == 0) {
    if (w < 1000) {
      const int j = w;
      const float x0 = x[0], x1 = x[1];
      float gir = fmaf(Wih0[2*j],        x0, Wih0[2*j+1]        * x1) + bih[j];
      float giz = fmaf(Wih0[2*(1000+j)], x0, Wih0[2*(1000+j)+1] * x1) + bih[1000 + j];
      float gin = fmaf(Wih0[2*(2000+j)], x0, Wih0[2*(2000+j)+1] * x1) + bih[2000 + j];
      float r = sigmoidf_(gir + dA + bhh[j]);
      float zz = sigmoidf_(giz + dB + bhh[1000 + j]);
      float n = tanhf(gin + r * (dC + bhh[2000 + j]));
      float h = (1.f - zz) * n + zz * hiddens[j];
      h_buf[j] = h;
      out[1 + j] = h;
      if (j == 0) out[0] = bout[0];          // init flow accumulator
    } else {
      const size_t rbase = 3000 + (size_t)(w - 1000) * 3;
      gh_ws[rbase - 3000 + 0] = dA + bhh[rbase + 0];
      gh_ws[rbase - 3000 + 1] = dB + bhh[rbase + 1];
      gh_ws[rbase - 3000 + 2] = dC + bhh[rbase + 2];
    }
  }
}

// One layer (l in 1..7), latency phase: block per neuron, one-shot wide load
// (each thread 4 independent float4s) + shuffle/LDS reduce + gate.
// Layer 7 also accumulates flow into out[0] (pre-set to b_out in phase A).
__global__ __launch_bounds__(256)
void gruB_layer(const int l,
                const float* __restrict__ hiddens,  // [8*1000]
                const float* __restrict__ Wih,      // [7*3000*1000]
                const float* __restrict__ bih,      // [8*3000]
                const float* __restrict__ gh_ws,    // [21000] (bhh included)
                const float* __restrict__ Wout,     // [1000]
                float* __restrict__ h_buf,          // [8*1000]
                float* __restrict__ out)            // [8001]
{
  const int t = threadIdx.x;
  const int j = blockIdx.x;                // neuron 0..999
  const float4* W4  = reinterpret_cast<const float4*>(
      Wih + (size_t)(l - 1) * 3000 * HIDDEN);
  const float4* hin = reinterpret_cast<const float4*>(
      h_buf + (size_t)(l - 1) * HIDDEN);

  float aR = 0.f, aZ = 0.f, aN = 0.f;
  if (t < K4) {
    float4 hv = hin[t];
    float4 wr = W4[(size_t)(j)        * K4 + t];
    float4 wz = W4[(size_t)(1000 + j) * K4 + t];
    float4 wn = W4[(size_t)(2000 + j) * K4 + t];
    aR = dot4(wr, hv, 0.f);
    aZ = dot4(wz, hv, 0.f);
    aN = dot4(wn, hv, 0.f);
  }
  #pragma unroll
  for (int off = 32; off; off >>= 1) {
    aR += __shfl_xor(aR, off);
    aZ += __shfl_xor(aZ, off);
    aN += __shfl_xor(aN, off);
  }
  __shared__ float s[4][3];
  const int wave = t >> 6, lane = t & 63;
  if (lane == 0) { s[wave][0] = aR; s[wave][1] = aZ; s[wave][2] = aN; }
  __syncthreads();
  if (t == 0) {
    float gir = s[0][0] + s[1][0] + s[2][0] + s[3][0] + bih[l*3000 + j];
    float giz = s[0][1] + s[1][1] + s[2][1] + s[3][1] + bih[l*3000 + 1000 + j];
    float gin = s[0][2] + s[1][2] + s[2][2] + s[3][2] + bih[l*3000 + 2000 + j];
    float ghr = gh_ws[(l-1)*3000 + j];
    float ghz = gh_ws[(l-1)*3000 + 1000 + j];
    float ghn = gh_ws[(l-1)*3000 + 2000 + j];
    float r = sigmoidf_(gir + ghr);
    float z = sigmoidf_(giz + ghz);
    float n = tanhf(gin + r * ghn);
    float h = (1.f - z) * n + z * hiddens[(size_t)l * HIDDEN + j];
    h_buf[l * HIDDEN + j] = h;
    out[1 + l * HIDDEN + j] = h;
    if (l == 7) atomicAdd(&out[0], Wout[j] * h);
  }
}

extern "C" void kernel_launch(void* const* d_in, const int* in_sizes, int n_in,
                              void* d_out, int out_size, void* d_ws, size_t ws_size,
                              hipStream_t stream) {
  const float* x       = (const float*)d_in[0];
  const float* hiddens = (const float*)d_in[1];
  const float* Wih0    = (const float*)d_in[2];
  const float* Wih     = (const float*)d_in[3];
  const float* Whh     = (const float*)d_in[4];
  const float* bih     = (const float*)d_in[5];
  const float* bhh     = (const float*)d_in[6];
  const float* Wout    = (const float*)d_in[7];
  const float* bout    = (const float*)d_in[8];
  float* out   = (float*)d_out;
  float* gh_ws = (float*)d_ws;          // 21000 floats (layers 1..7 gh)
  float* h_buf = gh_ws + 21000;         // 8000 floats

  gruA_gh<<<2000, 256, 0, stream>>>(x, hiddens, Wih0, Whh, bih, bhh, bout,
                                    gh_ws, h_buf, out);
  for (int l = 1; l < 8; ++l) {
    gruB_layer<<<1000, 256, 0, stream>>>(l, hiddens, Wih, bih, gh_ws, Wout,
                                         h_buf, out);
  }
}

// Round 9
// 68.257 us; speedup vs baseline: 10.7371x; 1.0099x over previous
//
#include <hip/hip_runtime.h>
#include <math.h>

#define HIDDEN 1000
#define K4 250        // float4 segments per 1000-float row
#define ROWS 12       // rows per streaming block

__device__ __forceinline__ float sigmoidf_(float x) {
  return 1.f / (1.f + expf(-x));
}

__device__ __forceinline__ float dot4(float4 a, float4 b, float acc) {
  return fmaf(a.x, b.x, fmaf(a.y, b.y, fmaf(a.z, b.z, fmaf(a.w, b.w, acc))));
}

// Wave-level dot of 1000 floats (looped shape, used only for layer-0 gate blocks).
__device__ __forceinline__ float wave_dot1000(const float* __restrict__ w,
                                              const float* __restrict__ v,
                                              int lane) {
  const float4* w4 = reinterpret_cast<const float4*>(w);
  const float4* v4 = reinterpret_cast<const float4*>(v);
  float acc = 0.f;
  for (int c = lane; c < K4; c += 64) {
    acc = dot4(w4[c], v4[c], acc);
  }
  #pragma unroll
  for (int off = 32; off; off >>= 1) acc += __shfl_xor(acc, off);
  return acc;
}

// Phase A:
//   blocks [0,250):    layer-0 neurons, wave per neuron (3 looped dots + gate -> h0)
//   blocks [250,2000): streaming blocks — 12 contiguous rows of one layer
//                      (layers 1..7). Thread t<250 holds v4 = h_l[4t..4t+3] and
//                      runs 12 independent load->dot4 chains (12 KB in flight
//                      per wave, no intermediate waits), then one reduce tail.
__global__ __launch_bounds__(256)
void gruA_stream(const float* __restrict__ x,        // [2]
                 const float* __restrict__ hiddens,  // [8*1000]
                 const float* __restrict__ Wih0,     // [3000*2]
                 const float* __restrict__ Whh,      // [8*3000*1000]
                 const float* __restrict__ bih,      // [8*3000]
                 const float* __restrict__ bhh,      // [8*3000]
                 const float* __restrict__ bout,     // [1]
                 float* __restrict__ gh_ws,          // [21000] layers 1..7
                 float* __restrict__ h_buf,          // [8*1000]
                 float* __restrict__ out)            // [8001]
{
  const int b = blockIdx.x;
  const int t = threadIdx.x;
  const int wv = t >> 6;
  const int lane = t & 63;

  if (b < 250) {
    // ---- layer-0 gate blocks (wave per neuron) ----
    const int j = b * 4 + wv;
    const float* h0 = hiddens;
    float ghr = wave_dot1000(Whh + (size_t)(j)        * HIDDEN, h0, lane) + bhh[j];
    float ghz = wave_dot1000(Whh + (size_t)(1000 + j) * HIDDEN, h0, lane) + bhh[1000 + j];
    float ghn = wave_dot1000(Whh + (size_t)(2000 + j) * HIDDEN, h0, lane) + bhh[2000 + j];
    if (lane == 0) {
      const float x0 = x[0], x1 = x[1];
      float gir = fmaf(Wih0[2*j],        x0, Wih0[2*j+1]        * x1) + bih[j];
      float giz = fmaf(Wih0[2*(1000+j)], x0, Wih0[2*(1000+j)+1] * x1) + bih[1000 + j];
      float gin = fmaf(Wih0[2*(2000+j)], x0, Wih0[2*(2000+j)+1] * x1) + bih[2000 + j];
      float r = sigmoidf_(gir + ghr);
      float z = sigmoidf_(giz + ghz);
      float n = tanhf(gin + r * ghn);
      float h = (1.f - z) * n + z * h0[j];
      h_buf[j] = h;
      out[1 + j] = h;
      if (j == 0) out[0] = bout[0];      // init flow accumulator
    }
    return;
  }

  // ---- streaming blocks: 12 rows of one layer (layers 1..7) ----
  const int s = b - 250;                     // 0..1749, 250 blocks per layer
  const int l = 1 + s / 250;                 // layer 1..7
  const size_t rowbase = (size_t)l * 3000 + (size_t)(s % 250) * ROWS;
  const float4* WH4 = reinterpret_cast<const float4*>(Whh);
  const float4* v4p = reinterpret_cast<const float4*>(hiddens + (size_t)l * HIDDEN);

  float acc[ROWS];
  #pragma unroll
  for (int r = 0; r < ROWS; ++r) acc[r] = 0.f;

  if (t < K4) {
    const float4 v4 = v4p[t];
    const float4* wbase = WH4 + rowbase * K4 + t;
    #pragma unroll
    for (int r = 0; r < ROWS; ++r) {
      float4 w = wbase[r * K4];              // 12 independent streaming loads
      acc[r] = dot4(w, v4, 0.f);
    }
  }

  // reduce: per-wave shuffle for each row, then cross-wave via LDS
  #pragma unroll
  for (int r = 0; r < ROWS; ++r) {
    float a = acc[r];
    #pragma unroll
    for (int o = 32; o; o >>= 1) a += __shfl_xor(a, o);
    acc[r] = a;
  }
  __shared__ float s_part[4][ROWS];
  if (lane == 0) {
    #pragma unroll
    for (int r = 0; r < ROWS; ++r) s_part[wv][r] = acc[r];
  }
  __syncthreads();
  if (t < ROWS) {
    const size_t row = rowbase + t;
    float g = s_part[0][t] + s_part[1][t] + s_part[2][t] + s_part[3][t]
            + bhh[row];
    gh_ws[row - 3000] = g;
  }
}

// One layer (l in 1..7): block per neuron, one-shot wide load + reduce + gate.
// Layer 7 also accumulates flow into out[0] (pre-set to b_out in phase A).
__global__ __launch_bounds__(256)
void gruB_layer(const int l,
                const float* __restrict__ hiddens,  // [8*1000]
                const float* __restrict__ Wih,      // [7*3000*1000]
                const float* __restrict__ bih,      // [8*3000]
                const float* __restrict__ gh_ws,    // [21000] (bhh included)
                const float* __restrict__ Wout,     // [1000]
                float* __restrict__ h_buf,          // [8*1000]
                float* __restrict__ out)            // [8001]
{
  const int t = threadIdx.x;
  const int j = blockIdx.x;                // neuron 0..999
  const float4* W4  = reinterpret_cast<const float4*>(
      Wih + (size_t)(l - 1) * 3000 * HIDDEN);
  const float4* hin = reinterpret_cast<const float4*>(
      h_buf + (size_t)(l - 1) * HIDDEN);

  float aR = 0.f, aZ = 0.f, aN = 0.f;
  if (t < K4) {
    float4 hv = hin[t];
    float4 wr = W4[(size_t)(j)        * K4 + t];
    float4 wz = W4[(size_t)(1000 + j) * K4 + t];
    float4 wn = W4[(size_t)(2000 + j) * K4 + t];
    aR = dot4(wr, hv, 0.f);
    aZ = dot4(wz, hv, 0.f);
    aN = dot4(wn, hv, 0.f);
  }
  #pragma unroll
  for (int off = 32; off; off >>= 1) {
    aR += __shfl_xor(aR, off);
    aZ += __shfl_xor(aZ, off);
    aN += __shfl_xor(aN, off);
  }
  __shared__ float s[4][3];
  const int wave = t >> 6, lane = t & 63;
  if (lane == 0) { s[wave][0] = aR; s[wave][1] = aZ; s[wave][2] = aN; }
  __syncthreads();
  if (t == 0) {
    float gir = s[0][0] + s[1][0] + s[2][0] + s[3][0] + bih[l*3000 + j];
    float giz = s[0][1] + s[1][1] + s[2][1] + s[3][1] + bih[l*3000 + 1000 + j];
    float gin = s[0][2] + s[1][2] + s[2][2] + s[3][2] + bih[l*3000 + 2000 + j];
    float ghr = gh_ws[(l-1)*3000 + j];
    float ghz = gh_ws[(l-1)*3000 + 1000 + j];
    float ghn = gh_ws[(l-1)*3000 + 2000 + j];
    float r = sigmoidf_(gir + ghr);
    float z = sigmoidf_(giz + ghz);
    float n = tanhf(gin + r * ghn);
    float h = (1.f - z) * n + z * hiddens[(size_t)l * HIDDEN + j];
    h_buf[l * HIDDEN + j] = h;
    out[1 + l * HIDDEN + j] = h;
    if (l == 7) atomicAdd(&out[0], Wout[j] * h);
  }
}

extern "C" void kernel_launch(void* const* d_in, const int* in_sizes, int n_in,
                              void* d_out, int out_size, void* d_ws, size_t ws_size,
                              hipStream_t stream) {
  const float* x       = (const float*)d_in[0];
  const float* hiddens = (const float*)d_in[1];
  const float* Wih0    = (const float*)d_in[2];
  const float* Wih     = (const float*)d_in[3];
  const float* Whh     = (const float*)d_in[4];
  const float* bih     = (const float*)d_in[5];
  const float* bhh     = (const float*)d_in[6];
  const float* Wout    = (const float*)d_in[7];
  const float* bout    = (const float*)d_in[8];
  float* out   = (float*)d_out;
  float* gh_ws = (float*)d_ws;          // 21000 floats (layers 1..7 gh)
  float* h_buf = gh_ws + 21000;         // 8000 floats

  gruA_stream<<<2000, 256, 0, stream>>>(x, hiddens, Wih0, Whh, bih, bhh, bout,
                                        gh_ws, h_buf, out);
  for (int l = 1; l < 8; ++l) {
    gruB_layer<<<1000, 256, 0, stream>>>(l, hiddens, Wih, bih, gh_ws, Wout,
                                         h_buf, out);
  }
}

// Round 10
// 67.279 us; speedup vs baseline: 10.8931x; 1.0145x over previous
//
#include <hip/hip_runtime.h>
#include <math.h>

#define HIDDEN 1000
#define K4 250        // float4 segments per 1000-float row

__device__ __forceinline__ float sigmoidf_(float x) {
  return 1.f / (1.f + expf(-x));
}

__device__ __forceinline__ float dot4(float4 a, float4 b, float acc) {
  return fmaf(a.x, b.x, fmaf(a.y, b.y, fmaf(a.z, b.z, fmaf(a.w, b.w, acc))));
}

// Wave-level dot of 1000 floats (looped, compiler fully unrolls the 4 steps).
__device__ __forceinline__ float wave_dot1000(const float* __restrict__ w,
                                              const float* __restrict__ v,
                                              int lane) {
  const float4* w4 = reinterpret_cast<const float4*>(w);
  const float4* v4 = reinterpret_cast<const float4*>(v);
  float acc = 0.f;
  #pragma unroll
  for (int c = lane; c < K4; c += 64) acc = dot4(w4[c], v4[c], acc);
  #pragma unroll
  for (int off = 32; off; off >>= 1) acc += __shfl_xor(acc, off);
  return acc;
}

// Phase A:
//   blocks [0,250):     layer-0 neurons, wave per neuron (3 looped dots + gate -> h0)
//   blocks [250,2875):  wave per 2 contiguous rows of layers 1..7 (21000 rows),
//                       looped x4 fully unrolled: 8 w-loads + 4 v-loads in
//                       flight per wave, one cheap tail (2 reduces, 2 stores).
__global__ __launch_bounds__(256)
void gruA2(const float* __restrict__ x,        // [2]
           const float* __restrict__ hiddens,  // [8*1000]
           const float* __restrict__ Wih0,     // [3000*2]
           const float* __restrict__ Whh,      // [8*3000*1000]
           const float* __restrict__ bih,      // [8*3000]
           const float* __restrict__ bhh,      // [8*3000]
           const float* __restrict__ bout,     // [1]
           float* __restrict__ gh_ws,          // [21000] layers 1..7
           float* __restrict__ h_buf,          // [8*1000]
           float* __restrict__ out)            // [8001]
{
  const int b = blockIdx.x;
  const int wv = threadIdx.x >> 6;
  const int lane = threadIdx.x & 63;

  if (b < 250) {
    // ---- layer-0 gate blocks (R3-proven shape) ----
    const int j = b * 4 + wv;
    const float* h0 = hiddens;
    float ghr = wave_dot1000(Whh + (size_t)(j)        * HIDDEN, h0, lane) + bhh[j];
    float ghz = wave_dot1000(Whh + (size_t)(1000 + j) * HIDDEN, h0, lane) + bhh[1000 + j];
    float ghn = wave_dot1000(Whh + (size_t)(2000 + j) * HIDDEN, h0, lane) + bhh[2000 + j];
    if (lane == 0) {
      const float x0 = x[0], x1 = x[1];
      float gir = fmaf(Wih0[2*j],        x0, Wih0[2*j+1]        * x1) + bih[j];
      float giz = fmaf(Wih0[2*(1000+j)], x0, Wih0[2*(1000+j)+1] * x1) + bih[1000 + j];
      float gin = fmaf(Wih0[2*(2000+j)], x0, Wih0[2*(2000+j)+1] * x1) + bih[2000 + j];
      float r = sigmoidf_(gir + ghr);
      float z = sigmoidf_(giz + ghz);
      float n = tanhf(gin + r * ghn);
      float h = (1.f - z) * n + z * h0[j];
      h_buf[j] = h;
      out[1 + j] = h;
      if (j == 0) out[0] = bout[0];      // init flow accumulator
    }
    return;
  }

  // ---- 2-rows-per-wave gh blocks (layers 1..7) ----
  const int w = (b - 250) * 4 + wv;            // 0..10499
  const size_t row = 3000 + (size_t)w * 2;     // rows 3000..23998 (pair never
                                               // straddles a layer: boundaries even)
  const int l = (int)(row / 3000);             // 1..7
  const float4* v4 = reinterpret_cast<const float4*>(hiddens + (size_t)l * HIDDEN);
  const float4* w0 = reinterpret_cast<const float4*>(Whh + row * HIDDEN);
  const float4* w1 = reinterpret_cast<const float4*>(Whh + (row + 1) * HIDDEN);

  float a0 = 0.f, a1 = 0.f;
  #pragma unroll
  for (int c = lane; c < K4; c += 64) {
    float4 vv = v4[c];
    float4 x0 = w0[c];
    float4 x1 = w1[c];
    a0 = dot4(x0, vv, a0);
    a1 = dot4(x1, vv, a1);
  }
  #pragma unroll
  for (int o = 32; o; o >>= 1) {
    a0 += __shfl_xor(a0, o);
    a1 += __shfl_xor(a1, o);
  }
  if (lane == 0) {
    gh_ws[row - 3000]     = a0 + bhh[row];
    gh_ws[row - 3000 + 1] = a1 + bhh[row + 1];
  }
}

// One layer (l in 1..7): block per neuron, one-shot wide load + reduce + gate.
// Layer 7 also accumulates flow into out[0] (pre-set to b_out in phase A).
__global__ __launch_bounds__(256)
void gruB_layer(const int l,
                const float* __restrict__ hiddens,  // [8*1000]
                const float* __restrict__ Wih,      // [7*3000*1000]
                const float* __restrict__ bih,      // [8*3000]
                const float* __restrict__ gh_ws,    // [21000] (bhh included)
                const float* __restrict__ Wout,     // [1000]
                float* __restrict__ h_buf,          // [8*1000]
                float* __restrict__ out)            // [8001]
{
  const int t = threadIdx.x;
  const int j = blockIdx.x;                // neuron 0..999
  const float4* W4  = reinterpret_cast<const float4*>(
      Wih + (size_t)(l - 1) * 3000 * HIDDEN);
  const float4* hin = reinterpret_cast<const float4*>(
      h_buf + (size_t)(l - 1) * HIDDEN);

  float aR = 0.f, aZ = 0.f, aN = 0.f;
  if (t < K4) {
    float4 hv = hin[t];
    float4 wr = W4[(size_t)(j)        * K4 + t];
    float4 wz = W4[(size_t)(1000 + j) * K4 + t];
    float4 wn = W4[(size_t)(2000 + j) * K4 + t];
    aR = dot4(wr, hv, 0.f);
    aZ = dot4(wz, hv, 0.f);
    aN = dot4(wn, hv, 0.f);
  }
  #pragma unroll
  for (int off = 32; off; off >>= 1) {
    aR += __shfl_xor(aR, off);
    aZ += __shfl_xor(aZ, off);
    aN += __shfl_xor(aN, off);
  }
  __shared__ float s[4][3];
  const int wave = t >> 6, lane = t & 63;
  if (lane == 0) { s[wave][0] = aR; s[wave][1] = aZ; s[wave][2] = aN; }
  __syncthreads();
  if (t == 0) {
    float gir = s[0][0] + s[1][0] + s[2][0] + s[3][0] + bih[l*3000 + j];
    float giz = s[0][1] + s[1][1] + s[2][1] + s[3][1] + bih[l*3000 + 1000 + j];
    float gin = s[0][2] + s[1][2] + s[2][2] + s[3][2] + bih[l*3000 + 2000 + j];
    float ghr = gh_ws[(l-1)*3000 + j];
    float ghz = gh_ws[(l-1)*3000 + 1000 + j];
    float ghn = gh_ws[(l-1)*3000 + 2000 + j];
    float r = sigmoidf_(gir + ghr);
    float z = sigmoidf_(giz + ghz);
    float n = tanhf(gin + r * ghn);
    float h = (1.f - z) * n + z * hiddens[(size_t)l * HIDDEN + j];
    h_buf[l * HIDDEN + j] = h;
    out[1 + l * HIDDEN + j] = h;
    if (l == 7) atomicAdd(&out[0], Wout[j] * h);
  }
}

extern "C" void kernel_launch(void* const* d_in, const int* in_sizes, int n_in,
                              void* d_out, int out_size, void* d_ws, size_t ws_size,
                              hipStream_t stream) {
  const float* x       = (const float*)d_in[0];
  const float* hiddens = (const float*)d_in[1];
  const float* Wih0    = (const float*)d_in[2];
  const float* Wih     = (const float*)d_in[3];
  const float* Whh     = (const float*)d_in[4];
  const float* bih     = (const float*)d_in[5];
  const float* bhh     = (const float*)d_in[6];
  const float* Wout    = (const float*)d_in[7];
  const float* bout    = (const float*)d_in[8];
  float* out   = (float*)d_out;
  float* gh_ws = (float*)d_ws;          // 21000 floats (layers 1..7 gh)
  float* h_buf = gh_ws + 21000;         // 8000 floats

  gruA2<<<2875, 256, 0, stream>>>(x, hiddens, Wih0, Whh, bih, bhh, bout,
                                  gh_ws, h_buf, out);
  for (int l = 1; l < 8; ++l) {
    gruB_layer<<<1000, 256, 0, stream>>>(l, hiddens, Wih, bih, gh_ws, Wout,
                                         h_buf, out);
  }
}